// Round 10
// baseline (234.884 us; speedup 1.0000x reference)
//
#include <hip/hip_runtime.h>
#include <stdint.h>

#define DIM   256
#define BATCH 8192
#define MCELL 4096

typedef unsigned long long u64;
typedef unsigned short u16;
typedef __attribute__((ext_vector_type(8))) short bf16x8;   // 8 bf16 = 4 VGPRs
typedef __attribute__((ext_vector_type(4))) float f32x4;

// ---------------- helpers ----------------
__device__ __forceinline__ u64 packMin(float v, unsigned idx) {
    unsigned u = __float_as_uint(v);
    u = (u & 0x80000000u) ? ~u : (u | 0x80000000u);   // order-preserving f32->u32
    return ((u64)u << 32) | (u64)idx;
}
__device__ __forceinline__ u16 f2bf(float f) {        // RN-even f32->bf16 (bits)
    unsigned u = __float_as_uint(f);
    u += 0x7fffu + ((u >> 16) & 1u);
    return (u16)(u >> 16);
}
__device__ __forceinline__ void gll16(const void* g, const char* l) {
    __builtin_amdgcn_global_load_lds(
        (const __attribute__((address_space(1))) unsigned int*)g,
        (__attribute__((address_space(3))) unsigned int*)l, 16, 0, 0);
}
__device__ __forceinline__ u64 umin64(u64 a, u64 b) { return a < b ? a : b; }
__device__ __forceinline__ u64 umax64(u64 a, u64 b) { return a < b ? b : a; }
__device__ __forceinline__ void ins2(u64& t1, u64& t2, u64 p) {
    u64 hi = umax64(p, t1);
    t1 = umin64(p, t1);
    t2 = umin64(t2, hi);
}
__device__ __forceinline__ void merge2(u64& a1, u64& a2, u64 o1, u64 o2) {
    u64 H1 = umax64(a1, o1);
    a1 = umin64(a1, o1);
    a2 = umin64(H1, umin64(a2, o2));
}
__device__ __forceinline__ void merge3(u64& a1, u64& a2, u64& a3,
                                       u64 o1, u64 o2, u64 o3) {
    u64 L1 = umin64(a1, o1), H1 = umax64(a1, o1);
    u64 L2 = umin64(a2, o2);
    u64 L3 = umin64(a3, o3);
    a1 = L1;
    a2 = umin64(H1, L2);
    a3 = umin64(umax64(H1, L2), L3);
}

// ---------------- prep: bf16 casts + w2 + scal, one launch ----------------
__global__ void k_prep(const float* __restrict__ X, const float* __restrict__ W,
                       u16* __restrict__ Xh, u16* __restrict__ Wh,
                       float* __restrict__ w2, const int* __restrict__ epoch_p,
                       float* __restrict__ scal) {
    const int blk = blockIdx.x;
    const int t = threadIdx.x;
    if (blk == 3072) {   // scal: E[64] table + alpha
        int raw = epoch_p[0];
        float ep = (raw >= 0 && raw < 100000) ? (float)raw : __int_as_float(raw);
        float radius = 32.0f - ep * (31.0f / 99.0f);
        float alpha  = 0.1f * (1.0f - ep / 100.0f);
        float rs = radius * 0.5f;
        float denom = 2.0f * rs * rs;
        if (t < 64)       scal[t]  = expf(-((float)(t * t)) / denom);
        else if (t == 64) scal[64] = alpha;
        return;
    }
    if (blk < 2048) {            // X cast
        const int fi = blk * 256 + t;
        float4 v = ((const float4*)X)[fi];
        ushort4 h = {f2bf(v.x), f2bf(v.y), f2bf(v.z), f2bf(v.w)};
        ((ushort4*)Xh)[fi] = h;
    } else {                     // W cast + w2
        const int fi = (blk - 2048) * 256 + t;
        float4 v = ((const float4*)W)[fi];
        ushort4 h = {f2bf(v.x), f2bf(v.y), f2bf(v.z), f2bf(v.w)};
        ((ushort4*)Wh)[fi] = h;
        float s = v.x * v.x + v.y * v.y + v.z * v.z + v.w * v.w;
        #pragma unroll
        for (int off = 32; off; off >>= 1) s += __shfl_down(s, off);
        if ((t & 63) == 0) w2[fi >> 6] = s;
    }
}

// ---------------- bf16 MFMA GEMM: X fully LDS-resident, barrier-free K-loop -
// block 128b x 128m, 4 waves (wr: m-half, wc: b-half), wave 64m x 64b.
// X panel (64 KB, swizzled) staged ONCE via global_load_lds; one __syncthreads
// (full vmcnt drain) and then 8 chunks of pure {4 ds_read_b128 + 4 direct
// W-loads (1-ahead pipeline) + 16 MFMA} with zero barriers/waitcnts.
__global__ __launch_bounds__(256, 2)
void k_gemm_argmin(const u16* __restrict__ Xh, const u16* __restrict__ Wh,
                   const float* __restrict__ w2, u64* __restrict__ slots) {
    __shared__ char smem[65536];
    const int wg = blockIdx.x;
    const int swz = (wg & 7) * 256 + (wg >> 3);   // XCD-chunked, bijective (2048%8==0)
    const int bt = swz >> 5;                      // 0..63
    const int mt = swz & 31;                      // 0..31
    const int tid = threadIdx.x;
    const int wid = tid >> 6;
    const int lane = tid & 63;
    const int wr = wid >> 1, wc = wid & 1;        // wr: m-half, wc: b-half
    const int b0 = bt * 128, m0 = mt * 128;
    const int rl = lane & 15, g = lane >> 4;

    // ---- X staging: all 8 chunks once (16 gll16/thread) ----
    const int sr0 = wid * 32 + (lane >> 2);
    const int sr1 = sr0 + 16;
    const int ss  = lane & 3;
    const int sg0 = ss ^ ((sr0 >> 1) & 3);        // pre-swizzled global slot
    const int sg1 = ss ^ ((sr1 >> 1) & 3);
    const size_t gA0 = (size_t)(b0 + sr0) * DIM + sg0 * 8;
    const size_t gA1 = (size_t)(b0 + sr1) * DIM + sg1 * 8;
    const int ldsA = wid * 2048;                  // wave-uniform within 8KB chunk region
    #pragma unroll
    for (int c = 0; c < 8; ++c) {
        char* base_ = smem + c * 8192;
        gll16(Xh + gA0 + c * 32, base_ + ldsA);
        gll16(Xh + gA1 + c * 32, base_ + ldsA + 1024);
    }

    // W direct per-lane source (row m0+wr*64+rl+16i, cols g*8 + c*32)
    const u16* wsrc = Wh + (size_t)(m0 + wr * 64 + rl) * DIM + g * 8;

    f32x4 acc[4][4];
    #pragma unroll
    for (int i = 0; i < 4; ++i)
        #pragma unroll
        for (int j = 0; j < 4; ++j) acc[i][j] = (f32x4){0.f, 0.f, 0.f, 0.f};

    __syncthreads();   // drains vmcnt(0)+lgkmcnt(0): X panel resident

    const int slot = g ^ ((rl >> 1) & 3);
    const int xoff = (wc * 64 + rl) * 64 + slot * 16;   // + j*1024 within chunk

    bf16x8 wf[4];
    #pragma unroll
    for (int i = 0; i < 4; ++i)
        wf[i] = *(const bf16x8*)(wsrc + (size_t)i * 16 * DIM);

    #pragma unroll
    for (int c = 0; c < 8; ++c) {
        bf16x8 wn[4];
        if (c < 7) {   // prefetch next chunk's W frags (1-ahead)
            #pragma unroll
            for (int i = 0; i < 4; ++i)
                wn[i] = *(const bf16x8*)(wsrc + (size_t)i * 16 * DIM + (c + 1) * 32);
        }
        const char* bufc = smem + c * 8192;
        #pragma unroll
        for (int j = 0; j < 4; ++j) {
            const bf16x8 xf = *(const bf16x8*)(bufc + xoff + j * 1024);
            #pragma unroll
            for (int i = 0; i < 4; ++i)   // D rows = m, D cols = b
                acc[i][j] = __builtin_amdgcn_mfma_f32_16x16x32_bf16(wf[i], xf, acc[i][j], 0, 0, 0);
        }
        if (c < 7) {
            #pragma unroll
            for (int i = 0; i < 4; ++i) wf[i] = wn[i];
        }
    }

    // ---- epilogue: m thread-local -> register top-2, 2 shuffle rounds ----
    float w2v[16];
    #pragma unroll
    for (int ii = 0; ii < 16; ++ii)
        w2v[ii] = w2[m0 + wr * 64 + (ii >> 2) * 16 + g * 4 + (ii & 3)];

    __syncthreads();                    // all waves done with X buffers; reuse smem
    u64* ex = (u64*)smem;               // [128 b-local][2 wr][2]

    #pragma unroll
    for (int j = 0; j < 4; ++j) {       // b-col = wc*64 + j*16 + rl
        u64 t1 = ~0ull, t2 = ~0ull;
        #pragma unroll
        for (int i = 0; i < 4; ++i)
            #pragma unroll
            for (int q = 0; q < 4; ++q) {
                const float d = fmaf(-2.0f, acc[i][j][q], w2v[i * 4 + q]);
                ins2(t1, t2, packMin(d, (unsigned)(m0 + wr * 64 + i * 16 + g * 4 + q)));
            }
        #pragma unroll
        for (int off = 16; off <= 32; off <<= 1) {   // merge across g
            const u64 o1 = __shfl_xor(t1, off);
            const u64 o2 = __shfl_xor(t2, off);
            merge2(t1, t2, o1, o2);
        }
        if (lane < 16) {                // g==0 lanes write
            u64* e = ex + ((size_t)(wc * 64 + j * 16 + rl) * 2 + wr) * 2;
            e[0] = t1; e[1] = t2;
        }
    }
    __syncthreads();
    if (tid < 128) {                    // merge wr halves, write global slots
        const u64* e = ex + (size_t)tid * 4;
        u64 a1 = e[0], a2 = e[1];
        merge2(a1, a2, e[2], e[3]);
        slots[(size_t)(b0 + tid) * 64 + mt]      = a1;   // [row][2 ranks][32 mt]
        slots[(size_t)(b0 + tid) * 64 + 32 + mt] = a2;
    }
}

// ---------------- merge slots -> exact top-3 recheck -> locs + bmu ----------
__global__ void k_merge(const u64* __restrict__ slots, const float* __restrict__ X,
                        const float* __restrict__ W, const float* __restrict__ w2,
                        float* __restrict__ out_locs, int* __restrict__ bmu) {
    const int wid = threadIdx.x >> 6, l = threadIdx.x & 63;
    const int row = blockIdx.x * 4 + wid;
    u64 t1 = slots[(size_t)row * 64 + l], t2 = ~0ull, t3 = ~0ull;
    #pragma unroll
    for (int off = 1; off <= 32; off <<= 1) {
        const u64 o1 = __shfl_xor(t1, off);
        const u64 o2 = __shfl_xor(t2, off);
        const u64 o3 = __shfl_xor(t3, off);
        merge3(t1, t2, t3, o1, o2, o3);
    }
    const int cand[3] = {(int)(t1 & 0xFFFFFFFFull), (int)(t2 & 0xFFFFFFFFull),
                         (int)(t3 & 0xFFFFFFFFull)};
    const float4 xv = *(const float4*)(X + (size_t)row * DIM + l * 4);
    float bd = 0.0f; int bm = -1;
    #pragma unroll
    for (int tix = 0; tix < 3; ++tix) {
        const int mc = cand[tix];
        const float4 wv = *(const float4*)(W + (size_t)mc * DIM + l * 4);
        float s = xv.x * wv.x + xv.y * wv.y + xv.z * wv.z + xv.w * wv.w;
        #pragma unroll
        for (int off = 1; off <= 32; off <<= 1) s += __shfl_xor(s, off);
        const float d = w2[mc] - 2.0f * s;
        if (bm < 0 || d < bd || (d == bd && mc < bm)) { bd = d; bm = mc; }
    }
    if (l == 0) {
        out_locs[row * 2 + 0] = (float)(bm >> 6);
        out_locs[row * 2 + 1] = (float)(bm & 63);
        bmu[row] = bm;
    }
}

// ---------------- gather: 4 cells/block, int4 scan, no atomics --------------
__global__ void k_gather(const int* __restrict__ bmu, const float* __restrict__ X,
                         float* __restrict__ A, float* __restrict__ cnt) {
    __shared__ int n;
    __shared__ u16 lst[BATCH];          // 16 KB
    const int bx = blockIdx.x;          // 1024
    const int t = threadIdx.x;
    if (t == 0) n = 0;
    __syncthreads();
    const int4* b4 = (const int4*)bmu;
    #pragma unroll
    for (int i = 0; i < BATCH / 4 / 256; ++i) {    // 8 int4 per thread
        const int idx = i * 256 + t;
        const int4 v = b4[idx];
        const int mv[4] = {v.x, v.y, v.z, v.w};
        #pragma unroll
        for (int q = 0; q < 4; ++q)
            if ((mv[q] >> 2) == bx)
                lst[atomicAdd(&n, 1)] = (u16)(((idx * 4 + q) << 2) | (mv[q] & 3));
    }
    __syncthreads();
    const int nn = n;
    #pragma unroll
    for (int cc = 0; cc < 4; ++cc) {
        float acc = 0.0f; int kc = 0;
        for (int k = 0; k < nn; ++k) {
            const u16 e = lst[k];                  // LDS broadcast
            if ((e & 3) == cc) { acc += X[(size_t)(e >> 2) * DIM + t]; ++kc; }
        }
        const int m = bx * 4 + cc;
        A[(size_t)m * DIM + t] = acc;
        if (t == 0) cnt[m] = (float)kc;
    }
}

// ---------------- conv pass 1: register-tiled, all-static indices -----------
template<int MJQ>
__device__ __forceinline__ void conv1_body(int gi, int t, const float* __restrict__ A,
                                           const float* __restrict__ scal,
                                           float* __restrict__ T1) {
    float acc[16];
    #pragma unroll
    for (int i = 0; i < 16; ++i) acc[i] = 0.0f;
    #pragma unroll
    for (int h = 0; h < 2; ++h) {
        float a[32];
        #pragma unroll
        for (int g2 = 0; g2 < 32; ++g2)
            a[g2] = A[(size_t)(gi * 64 + h * 32 + g2) * DIM + t];
        #pragma unroll
        for (int g2 = 0; g2 < 32; ++g2) {
            const int gj = h * 32 + g2;
            #pragma unroll
            for (int mjl = 0; mjl < 16; ++mjl) {
                const int mj = MJQ * 16 + mjl;
                const int dd = (mj >= gj) ? (mj - gj) : (gj - mj);   // static
                acc[mjl] = fmaf(scal[dd], a[g2], acc[mjl]);          // uniform s-load
            }
        }
    }
    #pragma unroll
    for (int mjl = 0; mjl < 16; ++mjl)
        T1[(size_t)(gi * 64 + MJQ * 16 + mjl) * DIM + t] = acc[mjl];
}

__global__ void k_conv1(const float* __restrict__ A, const float* __restrict__ scal,
                        float* __restrict__ T1, const float* __restrict__ cnt,
                        float* __restrict__ c1) {
    const int t = threadIdx.x;
    if (blockIdx.x == 64) {   // c1[gi][mj] = sum_gj E|mj-gj| cnt[gi][gj]
        #pragma unroll
        for (int k = 0; k < 4; ++k) {
            const int o = blockIdx.y * 1024 + k * 256 + t;
            const int gi = o >> 6, mj = o & 63;
            float acc = 0.0f;
            #pragma unroll
            for (int gj = 0; gj < 64; ++gj) {
                int dd = mj - gj; dd = dd < 0 ? -dd : dd;
                acc += scal[dd] * cnt[gi * 64 + gj];
            }
            c1[o] = acc;
        }
        return;
    }
    const int gi = blockIdx.x;
    switch (blockIdx.y) {
        case 0: conv1_body<0>(gi, t, A, scal, T1); break;
        case 1: conv1_body<1>(gi, t, A, scal, T1); break;
        case 2: conv1_body<2>(gi, t, A, scal, T1); break;
        default: conv1_body<3>(gi, t, A, scal, T1); break;
    }
}

// ---------------- conv pass 2: register-tiled + den + divide ----------------
template<int MIQ>
__device__ __forceinline__ void conv2_body(int mj, int t, const float* __restrict__ T1,
                                           const float* __restrict__ scal,
                                           const float* __restrict__ c1,
                                           float* __restrict__ outw) {
    __shared__ float dens[16];
    if (t < 16) {                       // den for mi = MIQ*16 + t
        const int mi = MIQ * 16 + t;
        float dn = 0.0f;
        for (int gi = 0; gi < 64; ++gi) {
            int dd = mi - gi; dd = dd < 0 ? -dd : dd;
            dn = fmaf(scal[dd], c1[gi * 64 + mj], dn);
        }
        dens[t] = dn;
    }
    float acc[16];
    #pragma unroll
    for (int i = 0; i < 16; ++i) acc[i] = 0.0f;
    #pragma unroll
    for (int h = 0; h < 2; ++h) {
        float t1r[32];
        #pragma unroll
        for (int g2 = 0; g2 < 32; ++g2)
            t1r[g2] = T1[(size_t)((h * 32 + g2) * 64 + mj) * DIM + t];
        #pragma unroll
        for (int g2 = 0; g2 < 32; ++g2) {
            const int gi = h * 32 + g2;
            #pragma unroll
            for (int mil = 0; mil < 16; ++mil) {
                const int mi = MIQ * 16 + mil;
                const int dd = (mi >= gi) ? (mi - gi) : (gi - mi);   // static
                acc[mil] = fmaf(scal[dd], t1r[g2], acc[mil]);
            }
        }
    }
    __syncthreads();
    const float al = scal[64];
    #pragma unroll
    for (int mil = 0; mil < 16; ++mil) {
        const int mi = MIQ * 16 + mil;
        outw[(size_t)(mi * 64 + mj) * DIM + t] = (al * acc[mil]) / (al * dens[mil] + 1e-12f);
    }
}

__global__ void k_conv2(const float* __restrict__ T1, const float* __restrict__ scal,
                        const float* __restrict__ c1, float* __restrict__ outw) {
    const int t = threadIdx.x;
    const int mj = blockIdx.x;
    switch (blockIdx.y) {
        case 0: conv2_body<0>(mj, t, T1, scal, c1, outw); break;
        case 1: conv2_body<1>(mj, t, T1, scal, c1, outw); break;
        case 2: conv2_body<2>(mj, t, T1, scal, c1, outw); break;
        default: conv2_body<3>(mj, t, T1, scal, c1, outw); break;
    }
}

// ---------------- launcher ----------------
extern "C" void kernel_launch(void* const* d_in, const int* in_sizes, int n_in,
                              void* d_out, int out_size, void* d_ws, size_t ws_size,
                              hipStream_t stream) {
    const float* X = (const float*)d_in[0];
    const float* W = (const float*)d_in[1];
    const int*   ep = (const int*)d_in[2];
    float* out = (float*)d_out;

    char* ws = (char*)d_ws;
    u64*   slots = (u64*)(ws + 0);                     // 4 MB [8192][64]
    float* T1    = (float*)(ws + 0);                   // alias (slots dead after merge)
    u16*   Xh    = (u16*)(ws + (4u << 20));            // 4 MB
    float* A     = (float*)(ws + (4u << 20));          // alias (Xh dead after gemm)
    float* cnt   = (float*)(ws + (8u << 20));          // 16 KB
    u16*   Wh    = (u16*)(ws + (8u << 20) + 16384);    // 2 MB
    float* w2    = (float*)(ws + (10u << 20) + 16384); // 16 KB
    float* scal  = (float*)(ws + (10u << 20) + 32768); // 65 floats
    float* c1    = (float*)(ws + (10u << 20) + 36864); // 16 KB
    int*   bmu   = (int*)(ws + (10u << 20) + 53248);   // 32 KB

    k_prep<<<3073, 256, 0, stream>>>(X, W, Xh, Wh, w2, ep, scal);
    k_gemm_argmin<<<2048, 256, 0, stream>>>(Xh, Wh, w2, slots);
    k_merge<<<2048, 256, 0, stream>>>(slots, X, W, w2, out, bmu);
    k_gather<<<1024, 256, 0, stream>>>(bmu, X, A, cnt);
    k_conv1<<<dim3(65, 4), 256, 0, stream>>>(A, scal, T1, cnt, c1);
    k_conv2<<<dim3(64, 4), 256, 0, stream>>>(T1, scal, c1, out + 16384);
}

// Round 11
// 168.537 us; speedup vs baseline: 1.3937x; 1.3937x over previous
//
#include <hip/hip_runtime.h>
#include <stdint.h>

#define DIM   256
#define BATCH 8192
#define MCELL 4096

typedef unsigned long long u64;
typedef unsigned short u16;
typedef __attribute__((ext_vector_type(8))) short bf16x8;   // 8 bf16 = 4 VGPRs
typedef __attribute__((ext_vector_type(4))) float f32x4;

// ---------------- helpers ----------------
__device__ __forceinline__ u64 packMin(float v, unsigned idx) {
    unsigned u = __float_as_uint(v);
    u = (u & 0x80000000u) ? ~u : (u | 0x80000000u);   // order-preserving f32->u32
    return ((u64)u << 32) | (u64)idx;
}
__device__ __forceinline__ u16 f2bf(float f) {        // RN-even f32->bf16 (bits)
    unsigned u = __float_as_uint(f);
    u += 0x7fffu + ((u >> 16) & 1u);
    return (u16)(u >> 16);
}
__device__ __forceinline__ void gll16(const void* g, const char* l) {
    __builtin_amdgcn_global_load_lds(
        (const __attribute__((address_space(1))) unsigned int*)g,
        (__attribute__((address_space(3))) unsigned int*)l, 16, 0, 0);
}
__device__ __forceinline__ u64 umin64(u64 a, u64 b) { return a < b ? a : b; }
__device__ __forceinline__ u64 umax64(u64 a, u64 b) { return a < b ? b : a; }
__device__ __forceinline__ void ins2(u64& t1, u64& t2, u64 p) {
    u64 hi = umax64(p, t1);
    t1 = umin64(p, t1);
    t2 = umin64(t2, hi);
}
__device__ __forceinline__ void merge2(u64& a1, u64& a2, u64 o1, u64 o2) {
    u64 H1 = umax64(a1, o1);
    a1 = umin64(a1, o1);
    a2 = umin64(H1, umin64(a2, o2));
}
__device__ __forceinline__ void merge3(u64& a1, u64& a2, u64& a3,
                                       u64 o1, u64 o2, u64 o3) {
    u64 L1 = umin64(a1, o1), H1 = umax64(a1, o1);
    u64 L2 = umin64(a2, o2);
    u64 L3 = umin64(a3, o3);
    a1 = L1;
    a2 = umin64(H1, L2);
    a3 = umin64(umax64(H1, L2), L3);
}

// ---------------- prep: bf16 casts + w2 + scal, one launch ----------------
__global__ void k_prep(const float* __restrict__ X, const float* __restrict__ W,
                       u16* __restrict__ Xh, u16* __restrict__ Wh,
                       float* __restrict__ w2, const int* __restrict__ epoch_p,
                       float* __restrict__ scal) {
    const int blk = blockIdx.x;
    const int t = threadIdx.x;
    if (blk == 3072) {   // scal: E[64] table + alpha
        int raw = epoch_p[0];
        float ep = (raw >= 0 && raw < 100000) ? (float)raw : __int_as_float(raw);
        float radius = 32.0f - ep * (31.0f / 99.0f);
        float alpha  = 0.1f * (1.0f - ep / 100.0f);
        float rs = radius * 0.5f;
        float denom = 2.0f * rs * rs;
        if (t < 64)       scal[t]  = expf(-((float)(t * t)) / denom);
        else if (t == 64) scal[64] = alpha;
        return;
    }
    if (blk < 2048) {            // X cast
        const int fi = blk * 256 + t;
        float4 v = ((const float4*)X)[fi];
        ushort4 h = {f2bf(v.x), f2bf(v.y), f2bf(v.z), f2bf(v.w)};
        ((ushort4*)Xh)[fi] = h;
    } else {                     // W cast + w2
        const int fi = (blk - 2048) * 256 + t;
        float4 v = ((const float4*)W)[fi];
        ushort4 h = {f2bf(v.x), f2bf(v.y), f2bf(v.z), f2bf(v.w)};
        ((ushort4*)Wh)[fi] = h;
        float s = v.x * v.x + v.y * v.y + v.z * v.z + v.w * v.w;
        #pragma unroll
        for (int off = 32; off; off >>= 1) s += __shfl_down(s, off);
        if ((t & 63) == 0) w2[fi >> 6] = s;
    }
}

// ---------------- hi-only bf16 MFMA GEMM (round-6 structure, known-best) ----
// block 128b x 128m, 4 waves (wr: m-half, wc: b-half), wave 64m x 64b.
// Shared staging: 3-buf {A 8KB, B 8KB}, 2-ahead, vmcnt(8); 2 barriers/chunk.
__global__ __launch_bounds__(256, 3)
void k_gemm_argmin(const u16* __restrict__ Xh, const u16* __restrict__ Wh,
                   const float* __restrict__ w2, u64* __restrict__ slots) {
    __shared__ char smem[49152];
    const int wg = blockIdx.x;
    const int swz = (wg & 7) * 256 + (wg >> 3);   // XCD-chunked, bijective (2048%8==0)
    const int bt = swz >> 5;                      // 0..63
    const int mt = swz & 31;                      // 0..31
    const int tid = threadIdx.x;
    const int wid = tid >> 6;
    const int lane = tid & 63;
    const int wr = wid >> 1, wc = wid & 1;        // wr: m-half, wc: b-half
    const int b0 = bt * 128, m0 = mt * 128;

    const int sr0 = wid * 32 + (lane >> 2);
    const int sr1 = sr0 + 16;
    const int ss  = lane & 3;
    const int sg0 = ss ^ ((sr0 >> 1) & 3);        // pre-swizzled global slot
    const int sg1 = ss ^ ((sr1 >> 1) & 3);
    const size_t gA0 = (size_t)(b0 + sr0) * DIM + sg0 * 8;   // X rows
    const size_t gA1 = (size_t)(b0 + sr1) * DIM + sg1 * 8;
    const size_t gB0 = (size_t)(m0 + sr0) * DIM + sg0 * 8;   // W rows
    const size_t gB1 = (size_t)(m0 + sr1) * DIM + sg1 * 8;
    const int ldsA = wid * 2048;                  // wave-uniform within 8KB region

    const int rl = lane & 15, g = lane >> 4;
    const int slot = g ^ ((rl >> 1) & 3);
    const int xoff = (wc * 64 + rl) * 64 + slot * 16;   // + j*1024 (X region @0)
    const int woff = (wr * 64 + rl) * 64 + slot * 16;   // + i*1024 (W region @8192)

    f32x4 acc[4][4];
    #pragma unroll
    for (int i = 0; i < 4; ++i)
        #pragma unroll
        for (int j = 0; j < 4; ++j) acc[i][j] = (f32x4){0.f, 0.f, 0.f, 0.f};

    #define STAGE(buf, c) do {                                                \
        char* base_ = smem + (buf) * 16384;                                   \
        const int co_ = (c) * 32;                                             \
        gll16(Xh + gA0 + co_, base_ + ldsA);                                  \
        gll16(Xh + gA1 + co_, base_ + ldsA + 1024);                           \
        gll16(Wh + gB0 + co_, base_ + 8192 + ldsA);                           \
        gll16(Wh + gB1 + co_, base_ + 8192 + ldsA + 1024);                    \
    } while (0)

    STAGE(0, 0);
    STAGE(1, 1);
    #pragma unroll
    for (int c = 0; c < 8; ++c) {
        if (c < 6) {
            STAGE((c + 2) % 3, c + 2);
            asm volatile("s_waitcnt vmcnt(8)" ::: "memory");  // chunk c landed
        } else if (c == 6) {
            asm volatile("s_waitcnt vmcnt(4)" ::: "memory");
        } else {
            asm volatile("s_waitcnt vmcnt(0)" ::: "memory");
        }
        __builtin_amdgcn_sched_barrier(0);
        __builtin_amdgcn_s_barrier();

        const char* bufc = smem + (c % 3) * 16384;
        bf16x8 wf[4];
        #pragma unroll
        for (int i = 0; i < 4; ++i)
            wf[i] = *(const bf16x8*)(bufc + 8192 + woff + i * 1024);
        __builtin_amdgcn_s_setprio(1);
        #pragma unroll
        for (int j = 0; j < 4; ++j) {
            const bf16x8 xf = *(const bf16x8*)(bufc + xoff + j * 1024);
            #pragma unroll
            for (int i = 0; i < 4; ++i)   // D rows = m, D cols = b
                acc[i][j] = __builtin_amdgcn_mfma_f32_16x16x32_bf16(wf[i], xf, acc[i][j], 0, 0, 0);
        }
        __builtin_amdgcn_s_setprio(0);
        __builtin_amdgcn_s_barrier();
    }
    #undef STAGE

    // ---- epilogue: m thread-local -> register top-2, 2 shuffle rounds ----
    float w2v[16];
    #pragma unroll
    for (int ii = 0; ii < 16; ++ii)
        w2v[ii] = w2[m0 + wr * 64 + (ii >> 2) * 16 + g * 4 + (ii & 3)];

    __syncthreads();                    // all waves done with buffers; reuse smem
    u64* ex = (u64*)smem;               // [128 b-local][2 wr][2]

    #pragma unroll
    for (int j = 0; j < 4; ++j) {       // b-col = wc*64 + j*16 + rl
        u64 t1 = ~0ull, t2 = ~0ull;
        #pragma unroll
        for (int i = 0; i < 4; ++i)
            #pragma unroll
            for (int q = 0; q < 4; ++q) {
                const float d = fmaf(-2.0f, acc[i][j][q], w2v[i * 4 + q]);
                ins2(t1, t2, packMin(d, (unsigned)(m0 + wr * 64 + i * 16 + g * 4 + q)));
            }
        #pragma unroll
        for (int off = 16; off <= 32; off <<= 1) {   // merge across g
            const u64 o1 = __shfl_xor(t1, off);
            const u64 o2 = __shfl_xor(t2, off);
            merge2(t1, t2, o1, o2);
        }
        if (lane < 16) {                // g==0 lanes write
            u64* e = ex + ((size_t)(wc * 64 + j * 16 + rl) * 2 + wr) * 2;
            e[0] = t1; e[1] = t2;
        }
    }
    __syncthreads();
    if (tid < 128) {                    // merge wr halves, write global slots
        const u64* e = ex + (size_t)tid * 4;
        u64 a1 = e[0], a2 = e[1];
        merge2(a1, a2, e[2], e[3]);
        slots[(size_t)(b0 + tid) * 64 + mt]      = a1;   // [row][2 ranks][32 mt]
        slots[(size_t)(b0 + tid) * 64 + 32 + mt] = a2;
    }
}

// ---------------- merge slots -> exact top-3 recheck -> locs/bmu + histogram -
__global__ void k_merge(const u64* __restrict__ slots, const float* __restrict__ X,
                        const float* __restrict__ W, const float* __restrict__ w2,
                        float* __restrict__ out_locs, int* __restrict__ bmu,
                        int* __restrict__ cnti) {
    const int wid = threadIdx.x >> 6, l = threadIdx.x & 63;
    const int row = blockIdx.x * 4 + wid;
    u64 t1 = slots[(size_t)row * 64 + l], t2 = ~0ull, t3 = ~0ull;
    #pragma unroll
    for (int off = 1; off <= 32; off <<= 1) {
        const u64 o1 = __shfl_xor(t1, off);
        const u64 o2 = __shfl_xor(t2, off);
        const u64 o3 = __shfl_xor(t3, off);
        merge3(t1, t2, t3, o1, o2, o3);
    }
    const int cand[3] = {(int)(t1 & 0xFFFFFFFFull), (int)(t2 & 0xFFFFFFFFull),
                         (int)(t3 & 0xFFFFFFFFull)};
    const float4 xv = *(const float4*)(X + (size_t)row * DIM + l * 4);
    float bd = 0.0f; int bm = -1;
    #pragma unroll
    for (int tix = 0; tix < 3; ++tix) {
        const int mc = cand[tix];
        const float4 wv = *(const float4*)(W + (size_t)mc * DIM + l * 4);
        float s = xv.x * wv.x + xv.y * wv.y + xv.z * wv.z + xv.w * wv.w;
        #pragma unroll
        for (int off = 1; off <= 32; off <<= 1) s += __shfl_xor(s, off);
        const float d = w2[mc] - 2.0f * s;
        if (bm < 0 || d < bd || (d == bd && mc < bm)) { bd = d; bm = mc; }
    }
    if (l == 0) {
        out_locs[row * 2 + 0] = (float)(bm >> 6);
        out_locs[row * 2 + 1] = (float)(bm & 63);
        bmu[row] = bm;
        atomicAdd(&cnti[bm], 1);        // histogram (8192 over 4096 addrs)
    }
}

// ---------------- scan: exclusive prefix over 4096 counts (1 block) ---------
__global__ void k_scan(const int* __restrict__ cnti, int* __restrict__ offs,
                       int* __restrict__ offs2, float* __restrict__ cntf) {
    __shared__ int wsum[16];
    const int t = threadIdx.x;          // 0..1023
    const int lane = t & 63, w = t >> 6;
    const int c0 = t * 4;
    const int v0 = cnti[c0], v1 = cnti[c0 + 1], v2 = cnti[c0 + 2], v3 = cnti[c0 + 3];
    const int s = v0 + v1 + v2 + v3;
    int x = s;                          // inclusive wave scan
    #pragma unroll
    for (int off = 1; off < 64; off <<= 1) {
        int y = __shfl_up(x, off);
        if (lane >= off) x += y;
    }
    if (lane == 63) wsum[w] = x;
    __syncthreads();
    if (t < 16) {                       // scan wave totals
        int y = wsum[t];
        #pragma unroll
        for (int off = 1; off < 16; off <<= 1) {
            int z = __shfl_up(y, off, 16);
            if (t >= off) y += z;
        }
        wsum[t] = y;
    }
    __syncthreads();
    int run = (w > 0 ? wsum[w - 1] : 0) + x - s;   // exclusive base
    offs[c0] = run; offs2[c0] = run; cntf[c0] = (float)v0; run += v0;
    offs[c0 + 1] = run; offs2[c0 + 1] = run; cntf[c0 + 1] = (float)v1; run += v1;
    offs[c0 + 2] = run; offs2[c0 + 2] = run; cntf[c0 + 2] = (float)v2; run += v2;
    offs[c0 + 3] = run; offs2[c0 + 3] = run; cntf[c0 + 3] = (float)v3; run += v3;
    if (t == 1023) offs[4096] = run;    // = BATCH
}

// ---------------- place: scatter row ids into cell-sorted order -------------
__global__ void k_place(const int* __restrict__ bmu, int* __restrict__ offs2,
                        int* __restrict__ order) {
    const int b = blockIdx.x * 256 + threadIdx.x;
    const int m = bmu[b];
    const int pos = atomicAdd(&offs2[m], 1);
    order[pos] = b;
}

// ---------------- gather: one block per cell, contiguous slice sum ----------
__global__ void k_gather(const int* __restrict__ offs, const int* __restrict__ order,
                         const float* __restrict__ X, float* __restrict__ A) {
    const int m = blockIdx.x;
    const int t = threadIdx.x;
    int k = offs[m];
    const int e = offs[m + 1];
    float a0 = 0.0f, a1 = 0.0f;
    for (; k + 1 < e; k += 2) {         // 2-row unroll for ILP
        a0 += X[(size_t)order[k] * DIM + t];
        a1 += X[(size_t)order[k + 1] * DIM + t];
    }
    if (k < e) a0 += X[(size_t)order[k] * DIM + t];
    A[(size_t)m * DIM + t] = a0 + a1;
}

// ---------------- conv pass 1: register-tiled, all-static indices -----------
template<int MJQ>
__device__ __forceinline__ void conv1_body(int gi, int t, const float* __restrict__ A,
                                           const float* __restrict__ scal,
                                           float* __restrict__ T1) {
    float acc[16];
    #pragma unroll
    for (int i = 0; i < 16; ++i) acc[i] = 0.0f;
    #pragma unroll
    for (int h = 0; h < 2; ++h) {
        float a[32];
        #pragma unroll
        for (int g2 = 0; g2 < 32; ++g2)
            a[g2] = A[(size_t)(gi * 64 + h * 32 + g2) * DIM + t];
        #pragma unroll
        for (int g2 = 0; g2 < 32; ++g2) {
            const int gj = h * 32 + g2;
            #pragma unroll
            for (int mjl = 0; mjl < 16; ++mjl) {
                const int mj = MJQ * 16 + mjl;
                const int dd = (mj >= gj) ? (mj - gj) : (gj - mj);   // static
                acc[mjl] = fmaf(scal[dd], a[g2], acc[mjl]);          // uniform s-load
            }
        }
    }
    #pragma unroll
    for (int mjl = 0; mjl < 16; ++mjl)
        T1[(size_t)(gi * 64 + MJQ * 16 + mjl) * DIM + t] = acc[mjl];
}

__global__ void k_conv1(const float* __restrict__ A, const float* __restrict__ scal,
                        float* __restrict__ T1, const float* __restrict__ cnt,
                        float* __restrict__ c1) {
    const int t = threadIdx.x;
    if (blockIdx.x == 64) {   // c1[gi][mj] = sum_gj E|mj-gj| cnt[gi][gj]
        #pragma unroll
        for (int k = 0; k < 4; ++k) {
            const int o = blockIdx.y * 1024 + k * 256 + t;
            const int gi = o >> 6, mj = o & 63;
            float acc = 0.0f;
            #pragma unroll
            for (int gj = 0; gj < 64; ++gj) {
                int dd = mj - gj; dd = dd < 0 ? -dd : dd;
                acc += scal[dd] * cnt[gi * 64 + gj];
            }
            c1[o] = acc;
        }
        return;
    }
    const int gi = blockIdx.x;
    switch (blockIdx.y) {
        case 0: conv1_body<0>(gi, t, A, scal, T1); break;
        case 1: conv1_body<1>(gi, t, A, scal, T1); break;
        case 2: conv1_body<2>(gi, t, A, scal, T1); break;
        default: conv1_body<3>(gi, t, A, scal, T1); break;
    }
}

// ---------------- conv pass 2: register-tiled + den + divide ----------------
template<int MIQ>
__device__ __forceinline__ void conv2_body(int mj, int t, const float* __restrict__ T1,
                                           const float* __restrict__ scal,
                                           const float* __restrict__ c1,
                                           float* __restrict__ outw) {
    __shared__ float dens[16];
    if (t < 16) {                       // den for mi = MIQ*16 + t
        const int mi = MIQ * 16 + t;
        float dn = 0.0f;
        for (int gi = 0; gi < 64; ++gi) {
            int dd = mi - gi; dd = dd < 0 ? -dd : dd;
            dn = fmaf(scal[dd], c1[gi * 64 + mj], dn);
        }
        dens[t] = dn;
    }
    float acc[16];
    #pragma unroll
    for (int i = 0; i < 16; ++i) acc[i] = 0.0f;
    #pragma unroll
    for (int h = 0; h < 2; ++h) {
        float t1r[32];
        #pragma unroll
        for (int g2 = 0; g2 < 32; ++g2)
            t1r[g2] = T1[(size_t)((h * 32 + g2) * 64 + mj) * DIM + t];
        #pragma unroll
        for (int g2 = 0; g2 < 32; ++g2) {
            const int gi = h * 32 + g2;
            #pragma unroll
            for (int mil = 0; mil < 16; ++mil) {
                const int mi = MIQ * 16 + mil;
                const int dd = (mi >= gi) ? (mi - gi) : (gi - mi);   // static
                acc[mil] = fmaf(scal[dd], t1r[g2], acc[mil]);
            }
        }
    }
    __syncthreads();
    const float al = scal[64];
    #pragma unroll
    for (int mil = 0; mil < 16; ++mil) {
        const int mi = MIQ * 16 + mil;
        outw[(size_t)(mi * 64 + mj) * DIM + t] = (al * acc[mil]) / (al * dens[mil] + 1e-12f);
    }
}

__global__ void k_conv2(const float* __restrict__ T1, const float* __restrict__ scal,
                        const float* __restrict__ c1, float* __restrict__ outw) {
    const int t = threadIdx.x;
    const int mj = blockIdx.x;
    switch (blockIdx.y) {
        case 0: conv2_body<0>(mj, t, T1, scal, c1, outw); break;
        case 1: conv2_body<1>(mj, t, T1, scal, c1, outw); break;
        case 2: conv2_body<2>(mj, t, T1, scal, c1, outw); break;
        default: conv2_body<3>(mj, t, T1, scal, c1, outw); break;
    }
}

// ---------------- launcher ----------------
extern "C" void kernel_launch(void* const* d_in, const int* in_sizes, int n_in,
                              void* d_out, int out_size, void* d_ws, size_t ws_size,
                              hipStream_t stream) {
    const float* X = (const float*)d_in[0];
    const float* W = (const float*)d_in[1];
    const int*   ep = (const int*)d_in[2];
    float* out = (float*)d_out;

    char* ws = (char*)d_ws;
    u64*   slots = (u64*)(ws + 0);                      // 4 MB [8192][64]
    float* T1    = (float*)(ws + 0);                    // alias (slots dead after merge)
    u16*   Xh    = (u16*)(ws + (4u << 20));             // 4 MB
    float* A     = (float*)(ws + (4u << 20));           // alias (Xh dead after gemm)
    float* cntf  = (float*)(ws + (8u << 20));           // 16 KB
    u16*   Wh    = (u16*)(ws + (8u << 20) + 16384);     // 2 MB
    float* w2    = (float*)(ws + (10u << 20) + 16384);  // 16 KB
    float* scal  = (float*)(ws + (10u << 20) + 32768);  // 65 floats
    int*   bmu   = (int*)(ws + (10u << 20) + 53248);    // 32 KB
    int*   cnti  = (int*)(ws + (10u << 20) + 86016);    // 16 KB
    int*   offs  = (int*)(ws + (10u << 20) + 102400);   // 16.4 KB (reserve 32 KB)
    int*   offs2 = (int*)(ws + (10u << 20) + 135168);   // 16 KB
    int*   order = (int*)(ws + (10u << 20) + 151552);   // 32 KB
    float* c1    = (float*)(ws + (10u << 20) + 184320); // 16 KB

    hipMemsetAsync(cnti, 0, 16384, stream);             // histogram zero

    k_prep<<<3073, 256, 0, stream>>>(X, W, Xh, Wh, w2, ep, scal);
    k_gemm_argmin<<<2048, 256, 0, stream>>>(Xh, Wh, w2, slots);
    k_merge<<<2048, 256, 0, stream>>>(slots, X, W, w2, out, bmu, cnti);
    k_scan<<<1, 1024, 0, stream>>>(cnti, offs, offs2, cntf);
    k_place<<<32, 256, 0, stream>>>(bmu, offs2, order);
    k_gather<<<MCELL, 256, 0, stream>>>(offs, order, X, A);
    k_conv1<<<dim3(65, 4), 256, 0, stream>>>(A, scal, T1, cntf, c1);
    k_conv2<<<dim3(64, 4), 256, 0, stream>>>(T1, scal, c1, out + 16384);
}